// Round 2
// 205.687 us; speedup vs baseline: 1.0151x; 1.0151x over previous
//
#include <hip/hip_runtime.h>
#include <hip/hip_bf16.h>
#include <math.h>

// B,T,D,H = 64,2048,256,5
constexpr int BB   = 64;
constexpr int TT   = 2048;
constexpr int DD   = 256;
constexpr int HH   = 5;
constexpr int SEG  = 64;             // segments per batch row
constexpr int TSEG = TT / SEG;       // 32 timesteps per block
constexpr int PSTR = 260;            // partial row stride: [0]=l, [1+d]=acc

// fast tanh: 1 - 2/(e^{2x}+1). |err| ~1e-6, threshold is 1.7e-3.
__device__ __forceinline__ float ftanh(float x) {
    float e = __expf(2.0f * x);
    return 1.0f - 2.0f * __builtin_amdgcn_rcpf(e + 1.0f);
}

// DPP add on the VALU pipe (vs __shfl_xor -> ds_swizzle on the LDS pipe).
template <int CTRL>
__device__ __forceinline__ float dpp_add(float x) {
    int s = __builtin_amdgcn_update_dpp(0, __float_as_int(x), CTRL, 0xf, 0xf, true);
    return x + __int_as_float(s);
}
// 32-lane-half sum via row_shr 1/2/4/8 + row_bcast15. Valid in lanes 31 and 63.
__device__ __forceinline__ float half_sum_dpp(float v) {
    v = dpp_add<0x111>(v);   // row_shr:1
    v = dpp_add<0x112>(v);   // row_shr:2
    v = dpp_add<0x114>(v);   // row_shr:4
    v = dpp_add<0x118>(v);   // row_shr:8
    v = dpp_add<0x142>(v);   // row_bcast15 -> lane31 = sum(0..31), lane63 = sum(32..63)
    return v;
}

// One block = (b, 32-timestep segment). x register-resident end-to-end.
// |intermed| <= sum|uwr| ~ 0.5 -> softmax WITHOUT max-shift; partials are
// pure sums. Cross-segment merge in a second kernel (kernel boundary does
// the L2 writeback once — per-block device fences cost +230us, see R4).
//
// R(this): the per-it tanh/intermed tail (2/64 active lanes, ~260 issue
// slots/lane) and the 256x-redundant lsum exp pass are replaced by a tiny
// LDS handoff + ONE 32-lane finish phase per block. Cuts ~40% of VALU
// issue so the kernel sits on the 128 MiB x_temp stream, not the ALU.
__global__ __launch_bounds__(256, 4)
void seg_kernel(const float* __restrict__ x_temp,
                const float* __restrict__ x_fea,
                const int* __restrict__ mask,            // bool -> int32 per harness
                const float* __restrict__ W_temp,        // (D,H) row-major
                const float* __restrict__ b_temp,
                const float* __restrict__ W_fea,         // (1,H)
                const float* __restrict__ b_fea,
                const float* __restrict__ uw,            // (H,H)
                float* __restrict__ part)                // (B*SEG, PSTR)
{
    __shared__ alignas(16) float im[2 * TSEG];     // interleaved {e_r, maskf_r}
    __shared__ alignas(16) float phl[TSEG][6];     // reduced dots ph[r][h] (+pad)
    __shared__ float lsh;                          // block lsum
    __shared__ alignas(16) float ldsw[8 * 264];    // per-(wave,half) acc partials

    const int tid  = threadIdx.x;
    const int l    = tid & 63;
    const int wave = tid >> 6;
    const int half = l >> 5;
    const int l32  = l & 31;
    const int blk  = blockIdx.x;
    const int b    = blk >> 6;          // blk / SEG
    const int seg  = blk & (SEG - 1);
    const int t0   = seg * TSEG;
    const size_t rowbase = (size_t)b * TT;
    const float* xbase = x_temp + (rowbase + t0) * (size_t)DD;

    if (tid < TSEG) im[2 * tid + 1] = mask[rowbase + t0 + tid] ? 1.0f : 0.0f;

    // ---- stage: 4 row-groups x 8 floats per lane, straight into registers ----
    const int dbase = l32 * 8;
    float4 xq[4][2];
#pragma unroll
    for (int it = 0; it < 4; ++it) {
        const float* p = xbase + it * (8 * DD) + wave * (2 * DD) + half * DD + dbase;
        xq[it][0] = *(const float4*)(p);
        xq[it][1] = *(const float4*)(p + 4);
    }

    // W rows dbase..dbase+7 are 40 consecutive floats at W_temp + dbase*5:
    // 10 float4 loads instead of 40 scalar dwords.
    float wvf[40];
    {
        const float4* wp = (const float4*)(W_temp + dbase * HH);
#pragma unroll
        for (int q = 0; q < 10; ++q) ((float4*)wvf)[q] = wp[q];
    }

    // ---- dot + DPP 32-half reduce; lanes 31/63 park ph[5] in LDS ----
#pragma unroll
    for (int it = 0; it < 4; ++it) {
        const int r = it * 8 + wave * 2 + half;
        const float4 a0 = xq[it][0], a1 = xq[it][1];
#pragma unroll
        for (int h = 0; h < HH; ++h) {
            float ph = a0.x * wvf[0 * HH + h] + a0.y * wvf[1 * HH + h]
                     + a0.z * wvf[2 * HH + h] + a0.w * wvf[3 * HH + h]
                     + a1.x * wvf[4 * HH + h] + a1.y * wvf[5 * HH + h]
                     + a1.z * wvf[6 * HH + h] + a1.w * wvf[7 * HH + h];
            ph = half_sum_dpp(ph);                // valid in lanes 31 / 63
            if (l32 == 31) phl[r][h] = ph;        // 2 lanes, r = wave*2+half row
        }
    }
    __syncthreads();

    // ---- finish phase: ONE 32-lane pass does tanh/intermed/exp/lsum for
    //      all 32 rows (was: per-it 2-active-lane tail + 256x-redundant exp) ----
    if (tid < TSEG) {
        const int r = tid;
        float wfea[HH], bfea[HH], btmp[HH], uwr[HH];
#pragma unroll
        for (int h = 0; h < HH; ++h) {
            wfea[h] = W_fea[h]; bfea[h] = b_fea[h]; btmp[h] = b_temp[h];
            float s = 0.f;
#pragma unroll
            for (int h2 = 0; h2 < HH; ++h2) s += uw[h * HH + h2];
            uwr[h] = s;  // sum(hadamard@uw+b,-1) = hadamard.uwr + const (cancels)
        }
        const float xf = x_fea[rowbase + t0 + r];
        float inter = 0.f;
#pragma unroll
        for (int h = 0; h < HH; ++h)
            inter += ftanh(phl[r][h] + btmp[h]) * ftanh(xf * wfea[h] + bfea[h]) * uwr[h];
        const float e = im[2 * r + 1] * __expf(inter);  // masked exp, no max-shift
        im[2 * r] = e;
        const float ls = half_sum_dpp(e);               // lane 31 = sum over 32 rows
        if (r == 31) lsh = ls;
    }
    __syncthreads();

    // ---- weighted accumulation from registers; w read once from LDS ----
    float acc8[8] = {0.f, 0.f, 0.f, 0.f, 0.f, 0.f, 0.f, 0.f};
#pragma unroll
    for (int it = 0; it < 4; ++it) {
        const int r = it * 8 + wave * 2 + half;
        const float w = im[2 * r];                      // e_r (unnormalized)
        const float4 a0 = xq[it][0], a1 = xq[it][1];
        acc8[0] = fmaf(w, a0.x, acc8[0]); acc8[1] = fmaf(w, a0.y, acc8[1]);
        acc8[2] = fmaf(w, a0.z, acc8[2]); acc8[3] = fmaf(w, a0.w, acc8[3]);
        acc8[4] = fmaf(w, a1.x, acc8[4]); acc8[5] = fmaf(w, a1.y, acc8[5]);
        acc8[6] = fmaf(w, a1.z, acc8[6]); acc8[7] = fmaf(w, a1.w, acc8[7]);
    }

    // ---- merge 8 (wave,half) slots via LDS ----
    const int slot = wave * 2 + half;
    float* wp = &ldsw[slot * 264 + dbase];
    *(float4*)(wp)     = make_float4(acc8[0], acc8[1], acc8[2], acc8[3]);
    *(float4*)(wp + 4) = make_float4(acc8[4], acc8[5], acc8[6], acc8[7]);
    __syncthreads();

    float accd = 0.f;
#pragma unroll
    for (int s = 0; s < 8; ++s) accd += ldsw[s * 264 + tid];

    float* pb = part + (size_t)blk * PSTR;
    if (tid == 0) pb[0] = lsh;
    pb[1 + tid] = accd;
}

// Merge SEG partials per batch row. Pure sums (no exp, no max-shift).
// 64 blocks x 1024 threads: 4 segment-groups x 256 d-columns per block,
// 16-deep coalesced reads + tiny LDS tree (was 64 sequential iterations
// on a 1-wavegroup block -> latency-bound).
__global__ __launch_bounds__(1024)
void combine_kernel(const float* __restrict__ part, float* __restrict__ out)
{
    __shared__ float red[4 * DD];
    __shared__ float dred[4];
    const int b = blockIdx.x;
    const int d = threadIdx.x & (DD - 1);
    const int g = threadIdx.x >> 8;       // segment-group 0..3
    const float* base = part + (size_t)b * SEG * PSTR;
    float den = 0.f, num = 0.f;
#pragma unroll
    for (int s = 0; s < 16; ++s) {
        const float* p = base + (size_t)(g * 16 + s) * PSTR;
        den += p[0];          // broadcast read
        num += p[1 + d];      // coalesced
    }
    red[g * DD + d] = num;
    if (d == 0) dred[g] = den;
    __syncthreads();
    if (g == 0) {
        const float n  = red[d] + red[DD + d] + red[2 * DD + d] + red[3 * DD + d];
        const float dn = dred[0] + dred[1] + dred[2] + dred[3];
        out[(size_t)b * DD + d] = n / dn;
    }
}

extern "C" void kernel_launch(void* const* d_in, const int* in_sizes, int n_in,
                              void* d_out, int out_size, void* d_ws, size_t ws_size,
                              hipStream_t stream) {
    const float* x_temp = (const float*)d_in[0];
    const float* x_fea  = (const float*)d_in[1];
    const int*   mask   = (const int*)d_in[2];
    const float* W_temp = (const float*)d_in[3];
    const float* b_temp = (const float*)d_in[4];
    const float* W_fea  = (const float*)d_in[5];
    const float* b_fea  = (const float*)d_in[6];
    // d_in[7] = b : constant across T, cancels in softmax — unused.
    const float* uw     = (const float*)d_in[8];

    float* part = (float*)d_ws;   // 4096 x 260 floats ~4.26 MB
    float* out  = (float*)d_out;

    seg_kernel<<<BB * SEG, 256, 0, stream>>>(x_temp, x_fea, mask, W_temp,
                                             b_temp, W_fea, b_fea, uw, part);
    combine_kernel<<<BB, 1024, 0, stream>>>(part, out);
}

// Round 4
// 203.856 us; speedup vs baseline: 1.0242x; 1.0090x over previous
//
#include <hip/hip_runtime.h>
#include <hip/hip_bf16.h>
#include <math.h>

// B,T,D,H = 64,2048,256,5
constexpr int BB   = 64;
constexpr int TT   = 2048;
constexpr int DD   = 256;
constexpr int HH   = 5;
constexpr int SEG  = 32;             // segments per batch row
constexpr int TSEG = TT / SEG;       // 64 timesteps per block
constexpr int PSTR = 260;            // partial row stride: [0]=l, [1+d]=acc

typedef float fvec4 __attribute__((ext_vector_type(4)));  // nontemporal-load-able

// fast tanh: 1 - 2/(e^{2x}+1). |err| ~1e-6, threshold is 1.7e-3.
__device__ __forceinline__ float ftanh(float x) {
    float e = __expf(2.0f * x);
    return 1.0f - 2.0f * __builtin_amdgcn_rcpf(e + 1.0f);
}

// DPP add on the VALU pipe (vs __shfl_xor -> ds_swizzle on the LDS pipe).
template <int CTRL>
__device__ __forceinline__ float dpp_add(float x) {
    int s = __builtin_amdgcn_update_dpp(0, __float_as_int(x), CTRL, 0xf, 0xf, true);
    return x + __int_as_float(s);
}
// 32-lane-half sum via row_shr 1/2/4/8 + row_bcast15. Valid in lanes 31 and 63.
__device__ __forceinline__ float half_sum_dpp(float v) {
    v = dpp_add<0x111>(v);   // row_shr:1
    v = dpp_add<0x112>(v);   // row_shr:2
    v = dpp_add<0x114>(v);   // row_shr:4
    v = dpp_add<0x118>(v);   // row_shr:8
    v = dpp_add<0x142>(v);   // row_bcast15 -> lane31 = sum(0..31), lane63 = sum(32..63)
    return v;
}

// One block = (b, 64-timestep segment). x register-resident end-to-end.
// |intermed| <= sum|uwr| ~ 0.5 -> softmax WITHOUT max-shift; partials are
// pure sums. Cross-segment merge in a second kernel (kernel boundary does
// the L2 writeback once — per-block device fences cost +230us, see R4).
//
// R2: TSEG 32->64 (2048 blocks): halves per-block epilogue count, part
// traffic (2.13 MB) and combine depth. VGPR ~130 -> launch_bounds(256,3)
// (cap ~170, no spill; 12 waves/CU; in-flight ~192 KiB/CU >> BDP so the
// x stream still saturates). x loads nontemporal: reuse is in registers,
// skip L2 allocation. R3: fvec4 ext-vector for the nontemporal builtin.
__global__ __launch_bounds__(256, 3)
void seg_kernel(const float* __restrict__ x_temp,
                const float* __restrict__ x_fea,
                const int* __restrict__ mask,            // bool -> int32 per harness
                const float* __restrict__ W_temp,        // (D,H) row-major
                const float* __restrict__ b_temp,
                const float* __restrict__ W_fea,         // (1,H)
                const float* __restrict__ b_fea,
                const float* __restrict__ uw,            // (H,H)
                float* __restrict__ part)                // (B*SEG, PSTR)
{
    __shared__ alignas(16) float im[2 * TSEG];     // interleaved {e_r, maskf_r}
    __shared__ alignas(16) float phl[TSEG][6];     // reduced dots ph[r][h] (+pad)
    __shared__ float lsh0, lsh1;                   // half lsums (rows 0..31 / 32..63)
    __shared__ alignas(16) float ldsw[8 * 264];    // per-(wave,half) acc partials

    const int tid  = threadIdx.x;
    const int l    = tid & 63;
    const int wave = tid >> 6;
    const int half = l >> 5;
    const int l32  = l & 31;
    const int blk  = blockIdx.x;
    const int b    = blk >> 5;          // blk / SEG
    const int seg  = blk & (SEG - 1);
    const int t0   = seg * TSEG;
    const size_t rowbase = (size_t)b * TT;
    const float* xbase = x_temp + (rowbase + t0) * (size_t)DD;

    if (tid < TSEG) im[2 * tid + 1] = mask[rowbase + t0 + tid] ? 1.0f : 0.0f;

    // ---- stage: 8 row-groups x 8 floats per lane, straight into registers ----
    const int dbase = l32 * 8;
    fvec4 xq[8][2];
#pragma unroll
    for (int it = 0; it < 8; ++it) {
        const float* p = xbase + it * (8 * DD) + wave * (2 * DD) + half * DD + dbase;
        xq[it][0] = __builtin_nontemporal_load((const fvec4*)(p));
        xq[it][1] = __builtin_nontemporal_load((const fvec4*)(p + 4));
    }

    // W rows dbase..dbase+7 are 40 consecutive floats at W_temp + dbase*5:
    // 10 float4 loads instead of 40 scalar dwords.
    float wvf[40];
    {
        const fvec4* wp = (const fvec4*)(W_temp + dbase * HH);
#pragma unroll
        for (int q = 0; q < 10; ++q) ((fvec4*)wvf)[q] = wp[q];
    }

    // ---- dot + DPP 32-half reduce; lanes 31/63 park ph[5] in LDS ----
#pragma unroll
    for (int it = 0; it < 8; ++it) {
        const int r = it * 8 + wave * 2 + half;
        const fvec4 a0 = xq[it][0], a1 = xq[it][1];
#pragma unroll
        for (int h = 0; h < HH; ++h) {
            float ph = a0[0] * wvf[0 * HH + h] + a0[1] * wvf[1 * HH + h]
                     + a0[2] * wvf[2 * HH + h] + a0[3] * wvf[3 * HH + h]
                     + a1[0] * wvf[4 * HH + h] + a1[1] * wvf[5 * HH + h]
                     + a1[2] * wvf[6 * HH + h] + a1[3] * wvf[7 * HH + h];
            ph = half_sum_dpp(ph);                // valid in lanes 31 / 63
            if (l32 == 31) phl[r][h] = ph;        // 2 lanes, unique r per (it,wave,half)
        }
    }
    __syncthreads();

    // ---- finish phase: ONE full wave (lanes 0..63 = rows 0..63) does
    //      tanh/intermed/exp/lsum for all 64 rows ----
    if (tid < TSEG) {
        const int r = tid;
        float wfea[HH], bfea[HH], btmp[HH], uwr[HH];
#pragma unroll
        for (int h = 0; h < HH; ++h) {
            wfea[h] = W_fea[h]; bfea[h] = b_fea[h]; btmp[h] = b_temp[h];
            float s = 0.f;
#pragma unroll
            for (int h2 = 0; h2 < HH; ++h2) s += uw[h * HH + h2];
            uwr[h] = s;  // sum(hadamard@uw+b,-1) = hadamard.uwr + const (cancels)
        }
        const float xf = x_fea[rowbase + t0 + r];
        float inter = 0.f;
#pragma unroll
        for (int h = 0; h < HH; ++h)
            inter += ftanh(phl[r][h] + btmp[h]) * ftanh(xf * wfea[h] + bfea[h]) * uwr[h];
        const float e = im[2 * r + 1] * __expf(inter);  // masked exp, no max-shift
        im[2 * r] = e;
        const float ls = half_sum_dpp(e);   // lane31: rows 0..31, lane63: rows 32..63
        if (r == 31) lsh0 = ls;
        if (r == 63) lsh1 = ls;
    }
    __syncthreads();

    // ---- weighted accumulation from registers; w read once from LDS ----
    float acc8[8] = {0.f, 0.f, 0.f, 0.f, 0.f, 0.f, 0.f, 0.f};
#pragma unroll
    for (int it = 0; it < 8; ++it) {
        const int r = it * 8 + wave * 2 + half;
        const float w = im[2 * r];                      // e_r (unnormalized)
        const fvec4 a0 = xq[it][0], a1 = xq[it][1];
        acc8[0] = fmaf(w, a0[0], acc8[0]); acc8[1] = fmaf(w, a0[1], acc8[1]);
        acc8[2] = fmaf(w, a0[2], acc8[2]); acc8[3] = fmaf(w, a0[3], acc8[3]);
        acc8[4] = fmaf(w, a1[0], acc8[4]); acc8[5] = fmaf(w, a1[1], acc8[5]);
        acc8[6] = fmaf(w, a1[2], acc8[6]); acc8[7] = fmaf(w, a1[3], acc8[7]);
    }

    // ---- merge 8 (wave,half) slots via LDS ----
    const int slot = wave * 2 + half;
    float* wp = &ldsw[slot * 264 + dbase];
    *(fvec4*)(wp)     = (fvec4){acc8[0], acc8[1], acc8[2], acc8[3]};
    *(fvec4*)(wp + 4) = (fvec4){acc8[4], acc8[5], acc8[6], acc8[7]};
    __syncthreads();

    float accd = 0.f;
#pragma unroll
    for (int s = 0; s < 8; ++s) accd += ldsw[s * 264 + tid];

    float* pb = part + (size_t)blk * PSTR;
    if (tid == 0) pb[0] = lsh0 + lsh1;
    pb[1 + tid] = accd;
}

// Merge SEG partials per batch row. Pure sums (no exp, no max-shift).
// 64 blocks x 1024 threads: 4 segment-groups x 256 d-columns per block,
// 8-deep coalesced reads + tiny LDS tree.
__global__ __launch_bounds__(1024)
void combine_kernel(const float* __restrict__ part, float* __restrict__ out)
{
    __shared__ float red[4 * DD];
    __shared__ float dred[4];
    const int b = blockIdx.x;
    const int d = threadIdx.x & (DD - 1);
    const int g = threadIdx.x >> 8;       // segment-group 0..3
    const float* base = part + (size_t)b * SEG * PSTR;
    float den = 0.f, num = 0.f;
#pragma unroll
    for (int s = 0; s < 8; ++s) {
        const float* p = base + (size_t)(g * 8 + s) * PSTR;
        den += p[0];          // broadcast read
        num += p[1 + d];      // coalesced
    }
    red[g * DD + d] = num;
    if (d == 0) dred[g] = den;
    __syncthreads();
    if (g == 0) {
        const float n  = red[d] + red[DD + d] + red[2 * DD + d] + red[3 * DD + d];
        const float dn = dred[0] + dred[1] + dred[2] + dred[3];
        out[(size_t)b * DD + d] = n / dn;
    }
}

extern "C" void kernel_launch(void* const* d_in, const int* in_sizes, int n_in,
                              void* d_out, int out_size, void* d_ws, size_t ws_size,
                              hipStream_t stream) {
    const float* x_temp = (const float*)d_in[0];
    const float* x_fea  = (const float*)d_in[1];
    const int*   mask   = (const int*)d_in[2];
    const float* W_temp = (const float*)d_in[3];
    const float* b_temp = (const float*)d_in[4];
    const float* W_fea  = (const float*)d_in[5];
    const float* b_fea  = (const float*)d_in[6];
    // d_in[7] = b : constant across T, cancels in softmax — unused.
    const float* uw     = (const float*)d_in[8];

    float* part = (float*)d_ws;   // 2048 x 260 floats ~2.13 MB
    float* out  = (float*)d_out;

    seg_kernel<<<BB * SEG, 256, 0, stream>>>(x_temp, x_fea, mask, W_temp,
                                             b_temp, W_fea, b_fea, uw, part);
    combine_kernel<<<BB, 1024, 0, stream>>>(part, out);
}

// Round 5
// 197.174 us; speedup vs baseline: 1.0589x; 1.0339x over previous
//
#include <hip/hip_runtime.h>
#include <hip/hip_bf16.h>
#include <math.h>

// B,T,D,H = 64,2048,256,5
constexpr int BB   = 64;
constexpr int TT   = 2048;
constexpr int DD   = 256;
constexpr int HH   = 5;
constexpr int SEG  = 32;             // segments per batch row
constexpr int TSEG = TT / SEG;       // 64 timesteps per block
constexpr int PSTR = 260;            // partial row stride: [0]=l, [1+d]=acc

typedef float fvec4 __attribute__((ext_vector_type(4)));  // nontemporal-load-able

// fast tanh: 1 - 2/(e^{2x}+1). |err| ~1e-6, threshold is 1.7e-3.
__device__ __forceinline__ float ftanh(float x) {
    float e = __expf(2.0f * x);
    return 1.0f - 2.0f * __builtin_amdgcn_rcpf(e + 1.0f);
}

// DPP add on the VALU pipe (vs __shfl_xor -> ds_swizzle on the LDS pipe).
template <int CTRL>
__device__ __forceinline__ float dpp_add(float x) {
    int s = __builtin_amdgcn_update_dpp(0, __float_as_int(x), CTRL, 0xf, 0xf, true);
    return x + __int_as_float(s);
}
// 32-lane-half sum via row_shr 1/2/4/8 + row_bcast15. Valid in lanes 31 and 63.
__device__ __forceinline__ float half_sum_dpp(float v) {
    v = dpp_add<0x111>(v);   // row_shr:1
    v = dpp_add<0x112>(v);   // row_shr:2
    v = dpp_add<0x114>(v);   // row_shr:4
    v = dpp_add<0x118>(v);   // row_shr:8
    v = dpp_add<0x142>(v);   // row_bcast15 -> lane31 = sum(0..31), lane63 = sum(32..63)
    return v;
}

// One block = (b, 64-timestep segment). x register-resident end-to-end.
// |intermed| <= sum|uwr| ~ 0.5 -> softmax WITHOUT max-shift; partials are
// pure sums. Cross-segment merge in a second kernel.
//
// R4: NT loads + GAPPED lane mapping (l32*8, two 16B loads 16B apart) meant
// each instruction's wave footprint was half-density -> with no L2 allocate
// the second load refetched the same DRAM sectors (~2x x_temp read traffic).
// Fix: contiguous mapping — lane l32 loads floats [4*l32,4*l32+4) and
// [128+4*l32, ...): each instruction covers a gap-free 512B block. NT kept
// (pure stream, no L2 pollution). W loads stay cached (shared by all blocks).
__global__ __launch_bounds__(256, 3)
void seg_kernel(const float* __restrict__ x_temp,
                const float* __restrict__ x_fea,
                const int* __restrict__ mask,            // bool -> int32 per harness
                const float* __restrict__ W_temp,        // (D,H) row-major
                const float* __restrict__ b_temp,
                const float* __restrict__ W_fea,         // (1,H)
                const float* __restrict__ b_fea,
                const float* __restrict__ uw,            // (H,H)
                float* __restrict__ part)                // (B*SEG, PSTR)
{
    __shared__ alignas(16) float im[2 * TSEG];     // interleaved {e_r, maskf_r}
    __shared__ alignas(16) float phl[TSEG][6];     // reduced dots ph[r][h] (+pad)
    __shared__ float lsh0, lsh1;                   // half lsums (rows 0..31 / 32..63)
    __shared__ alignas(16) float ldsw[8 * 264];    // per-(wave,half) acc partials

    const int tid  = threadIdx.x;
    const int l    = tid & 63;
    const int wave = tid >> 6;
    const int half = l >> 5;
    const int l32  = l & 31;
    const int blk  = blockIdx.x;
    const int b    = blk >> 5;          // blk / SEG
    const int seg  = blk & (SEG - 1);
    const int t0   = seg * TSEG;
    const size_t rowbase = (size_t)b * TT;
    const float* xbase = x_temp + (rowbase + t0) * (size_t)DD;

    if (tid < TSEG) im[2 * tid + 1] = mask[rowbase + t0 + tid] ? 1.0f : 0.0f;

    // ---- stage: 8 rows per (wave,half); lane owns d0..d0+3 and 128+d0..+3 ----
    const int d0 = l32 * 4;
    fvec4 xq[8][2];
#pragma unroll
    for (int it = 0; it < 8; ++it) {
        const float* p = xbase + (it * 8 + wave * 2 + half) * DD;
        xq[it][0] = __builtin_nontemporal_load((const fvec4*)(p + d0));
        xq[it][1] = __builtin_nontemporal_load((const fvec4*)(p + 128 + d0));
    }

    // W rows d0..d0+3: 20 consecutive floats at W_temp + d0*5 (80B-aligned);
    // W rows 128+d0..: 20 floats at W_temp + (128+d0)*5.
    float wv0[20], wv1[20];
    {
        const fvec4* wp0 = (const fvec4*)(W_temp + d0 * HH);
        const fvec4* wp1 = (const fvec4*)(W_temp + (128 + d0) * HH);
#pragma unroll
        for (int q = 0; q < 5; ++q) { ((fvec4*)wv0)[q] = wp0[q]; ((fvec4*)wv1)[q] = wp1[q]; }
    }

    // ---- dot + DPP 32-half reduce; lanes 31/63 park ph[5] in LDS ----
#pragma unroll
    for (int it = 0; it < 8; ++it) {
        const int r = it * 8 + wave * 2 + half;
        const fvec4 a0 = xq[it][0], a1 = xq[it][1];
#pragma unroll
        for (int h = 0; h < HH; ++h) {
            float ph = a0[0] * wv0[0 * HH + h] + a0[1] * wv0[1 * HH + h]
                     + a0[2] * wv0[2 * HH + h] + a0[3] * wv0[3 * HH + h]
                     + a1[0] * wv1[0 * HH + h] + a1[1] * wv1[1 * HH + h]
                     + a1[2] * wv1[2 * HH + h] + a1[3] * wv1[3 * HH + h];
            ph = half_sum_dpp(ph);                // valid in lanes 31 / 63
            if (l32 == 31) phl[r][h] = ph;        // 2 lanes, unique r per (it,wave,half)
        }
    }
    __syncthreads();

    // ---- finish phase: ONE full wave (lanes 0..63 = rows 0..63) ----
    if (tid < TSEG) {
        const int r = tid;
        float wfea[HH], bfea[HH], btmp[HH], uwr[HH];
#pragma unroll
        for (int h = 0; h < HH; ++h) {
            wfea[h] = W_fea[h]; bfea[h] = b_fea[h]; btmp[h] = b_temp[h];
            float s = 0.f;
#pragma unroll
            for (int h2 = 0; h2 < HH; ++h2) s += uw[h * HH + h2];
            uwr[h] = s;  // sum(hadamard@uw+b,-1) = hadamard.uwr + const (cancels)
        }
        const float xf = x_fea[rowbase + t0 + r];
        float inter = 0.f;
#pragma unroll
        for (int h = 0; h < HH; ++h)
            inter += ftanh(phl[r][h] + btmp[h]) * ftanh(xf * wfea[h] + bfea[h]) * uwr[h];
        const float e = im[2 * r + 1] * __expf(inter);  // masked exp, no max-shift
        im[2 * r] = e;
        const float ls = half_sum_dpp(e);   // lane31: rows 0..31, lane63: rows 32..63
        if (r == 31) lsh0 = ls;
        if (r == 63) lsh1 = ls;
    }
    __syncthreads();

    // ---- weighted accumulation from registers; w read once from LDS ----
    float acc8[8] = {0.f, 0.f, 0.f, 0.f, 0.f, 0.f, 0.f, 0.f};
#pragma unroll
    for (int it = 0; it < 8; ++it) {
        const int r = it * 8 + wave * 2 + half;
        const float w = im[2 * r];                      // e_r (unnormalized)
        const fvec4 a0 = xq[it][0], a1 = xq[it][1];
        acc8[0] = fmaf(w, a0[0], acc8[0]); acc8[1] = fmaf(w, a0[1], acc8[1]);
        acc8[2] = fmaf(w, a0[2], acc8[2]); acc8[3] = fmaf(w, a0[3], acc8[3]);
        acc8[4] = fmaf(w, a1[0], acc8[4]); acc8[5] = fmaf(w, a1[1], acc8[5]);
        acc8[6] = fmaf(w, a1[2], acc8[6]); acc8[7] = fmaf(w, a1[3], acc8[7]);
    }

    // ---- merge 8 (wave,half) slots via LDS; lane owns d0 block + 128+d0 block ----
    const int slot = wave * 2 + half;
    float* wp = &ldsw[slot * 264];
    *(fvec4*)(wp + d0)       = (fvec4){acc8[0], acc8[1], acc8[2], acc8[3]};
    *(fvec4*)(wp + 128 + d0) = (fvec4){acc8[4], acc8[5], acc8[6], acc8[7]};
    __syncthreads();

    float accd = 0.f;
#pragma unroll
    for (int s = 0; s < 8; ++s) accd += ldsw[s * 264 + tid];

    float* pb = part + (size_t)blk * PSTR;
    if (tid == 0) pb[0] = lsh0 + lsh1;
    pb[1 + tid] = accd;
}

// Merge SEG partials per batch row. Pure sums (no exp, no max-shift).
// 64 blocks x 1024 threads: 4 segment-groups x 256 d-columns per block,
// 8-deep coalesced reads + tiny LDS tree.
__global__ __launch_bounds__(1024)
void combine_kernel(const float* __restrict__ part, float* __restrict__ out)
{
    __shared__ float red[4 * DD];
    __shared__ float dred[4];
    const int b = blockIdx.x;
    const int d = threadIdx.x & (DD - 1);
    const int g = threadIdx.x >> 8;       // segment-group 0..3
    const float* base = part + (size_t)b * SEG * PSTR;
    float den = 0.f, num = 0.f;
#pragma unroll
    for (int s = 0; s < 8; ++s) {
        const float* p = base + (size_t)(g * 8 + s) * PSTR;
        den += p[0];          // broadcast read
        num += p[1 + d];      // coalesced
    }
    red[g * DD + d] = num;
    if (d == 0) dred[g] = den;
    __syncthreads();
    if (g == 0) {
        const float n  = red[d] + red[DD + d] + red[2 * DD + d] + red[3 * DD + d];
        const float dn = dred[0] + dred[1] + dred[2] + dred[3];
        out[(size_t)b * DD + d] = n / dn;
    }
}

extern "C" void kernel_launch(void* const* d_in, const int* in_sizes, int n_in,
                              void* d_out, int out_size, void* d_ws, size_t ws_size,
                              hipStream_t stream) {
    const float* x_temp = (const float*)d_in[0];
    const float* x_fea  = (const float*)d_in[1];
    const int*   mask   = (const int*)d_in[2];
    const float* W_temp = (const float*)d_in[3];
    const float* b_temp = (const float*)d_in[4];
    const float* W_fea  = (const float*)d_in[5];
    const float* b_fea  = (const float*)d_in[6];
    // d_in[7] = b : constant across T, cancels in softmax — unused.
    const float* uw     = (const float*)d_in[8];

    float* part = (float*)d_ws;   // 2048 x 260 floats ~2.13 MB
    float* out  = (float*)d_out;

    seg_kernel<<<BB * SEG, 256, 0, stream>>>(x_temp, x_fea, mask, W_temp,
                                             b_temp, W_fea, b_fea, uw, part);
    combine_kernel<<<BB, 1024, 0, stream>>>(part, out);
}